// Round 1
// baseline (13339.682 us; speedup 1.0000x reference)
//
#include <hip/hip_runtime.h>
#include <math.h>

#define BB 256   // batch
#define TT 128   // time steps
#define DD 256   // input dim
#define UU 512   // units

__device__ __forceinline__ float hsig(float x) {
    return fminf(fmaxf(0.2f * x + 0.5f, 0.0f), 1.0f);
}

// Tiled fp32 GEMM: C[256 x N] = A[256 x K] @ W[K x N] + bias[N]
// BM=32, BN=64, BK=16, 256 threads, 2x4 micro-tile per thread.
__global__ __launch_bounds__(256) void gemm_bias(
    const float* __restrict__ A, int lda,
    const float* __restrict__ W,
    const float* __restrict__ bias,
    float* __restrict__ C,
    int K, int N)
{
    __shared__ float As[16][32];   // [k][m]
    __shared__ float Ws[16][64];   // [k][n]
    const int bn = blockIdx.x * 64;
    const int bm = blockIdx.y * 32;
    const int tid = threadIdx.x;
    const int tx = tid & 15;        // n-dir (0..15)
    const int ty = tid >> 4;        // m-dir (0..15)

    const int arow = tid >> 3;         // 0..31
    const int acol = (tid & 7) * 2;    // 0,2,..,14
    const int wrow = tid >> 4;         // 0..15
    const int wcol = (tid & 15) * 4;   // 0,4,..,60

    float acc[2][4] = {{0.f,0.f,0.f,0.f},{0.f,0.f,0.f,0.f}};

    for (int k0 = 0; k0 < K; k0 += 16) {
        float2 av = *(const float2*)(A + (size_t)(bm + arow) * lda + k0 + acol);
        float4 wv = *(const float4*)(W + (size_t)(k0 + wrow) * N + bn + wcol);
        As[acol][arow]     = av.x;
        As[acol + 1][arow] = av.y;
        *(float4*)&Ws[wrow][wcol] = wv;
        __syncthreads();
#pragma unroll
        for (int kk = 0; kk < 16; ++kk) {
            float a0 = As[kk][ty * 2];
            float a1 = As[kk][ty * 2 + 1];
#pragma unroll
            for (int j = 0; j < 4; ++j) {
                float b = Ws[kk][tx * 4 + j];
                acc[0][j] += a0 * b;
                acc[1][j] += a1 * b;
            }
        }
        __syncthreads();
    }

    float4 bv = *(const float4*)(bias + bn + tx * 4);
#pragma unroll
    for (int i = 0; i < 2; ++i) {
        int row = bm + ty * 2 + i;
        float4 o;
        o.x = acc[i][0] + bv.x;
        o.y = acc[i][1] + bv.y;
        o.z = acc[i][2] + bv.z;
        o.w = acc[i][3] + bv.w;
        *(float4*)(C + (size_t)row * N + bn + tx * 4) = o;
    }
}

// gates from xg (B x 5U) and hg (B x 4U): h1 = z*h + (1-z)*hh; stash pre_l
__global__ __launch_bounds__(256) void elem_gates(
    const float* __restrict__ xg, const float* __restrict__ hg,
    const float* __restrict__ h,
    float* __restrict__ h1, float* __restrict__ pre_l)
{
    int i = blockIdx.x * 256 + threadIdx.x;   // 0..B*U
    int b = i >> 9;          // /U
    int u = i & (UU - 1);    // %U
    const float* xb = xg + (size_t)b * (5 * UU);
    const float* hb = hg + (size_t)b * (4 * UU);
    float z  = hsig(xb[u]          + hb[u]);
    float r  = hsig(xb[UU + u]     + hb[UU + u]);
    float hh = tanhf(xb[2 * UU + u] + r * hb[2 * UU + u]);
    float h1v = z * h[i] + (1.0f - z) * hh;
    h1[i]    = h1v;
    pre_l[i] = xb[3 * UU + u] + hb[3 * UU + u];
}

// transition layer: h1 = zt*h1 + (1-zt)*tanh(rt*th)
__global__ __launch_bounds__(256) void elem_t(
    const float* __restrict__ tg, float* __restrict__ h1)
{
    int i = blockIdx.x * 256 + threadIdx.x;
    int b = i >> 9;
    int u = i & (UU - 1);
    const float* tb_ = tg + (size_t)b * (3 * UU);
    float zt = hsig(tb_[u]);
    float rt = hsig(tb_[UU + u]);
    float ht = tanhf(rt * tb_[2 * UU + u]);
    h1[i] = zt * h1[i] + (1.0f - zt) * ht;
}

// last transition layer + output gate + write ys[b][t][u], update h
__global__ __launch_bounds__(256) void elem_final(
    const float* __restrict__ tg, const float* __restrict__ pre_l,
    const float* __restrict__ xg,
    const float* __restrict__ h1_in,
    float* __restrict__ h, float* __restrict__ out, int t)
{
    int i = blockIdx.x * 256 + threadIdx.x;
    int b = i >> 9;
    int u = i & (UU - 1);
    const float* tb_ = tg + (size_t)b * (3 * UU);
    float zt = hsig(tb_[u]);
    float rt = hsig(tb_[UU + u]);
    float ht = tanhf(rt * tb_[2 * UU + u]);
    float h1v = zt * h1_in[i] + (1.0f - zt) * ht;
    float l   = hsig(pre_l[i]);
    float xl2 = xg[(size_t)b * (5 * UU) + 4 * UU + u];
    float ho  = l * h1v + (1.0f - l) * tanhf(xl2);
    out[(size_t)b * TT * UU + (size_t)t * UU + u] = ho;
    h[i] = ho;
}

extern "C" void kernel_launch(void* const* d_in, const int* in_sizes, int n_in,
                              void* d_out, int out_size, void* d_ws, size_t ws_size,
                              hipStream_t stream) {
    const float* x      = (const float*)d_in[0];  // (B,T,D)
    const float* h0     = (const float*)d_in[1];  // (B,U)
    const float* kernel = (const float*)d_in[2];  // (D,5U)
    const float* rk     = (const float*)d_in[3];  // (U,4U)
    const float* tk     = (const float*)d_in[4];  // (2,U,3U)
    const float* bias   = (const float*)d_in[5];  // (2,5U)
    const float* tb     = (const float*)d_in[6];  // (2,3U)
    float* out = (float*)d_out;
    float* ws  = (float*)d_ws;

    // workspace layout (floats)
    float* xg    = ws;                       // B*5U = 655360
    float* hg    = xg + (size_t)BB * 5 * UU; // B*4U = 524288 (reused as tg)
    float* tg    = hg;                       // alias: hg consumed before tg written
    float* h     = hg + (size_t)BB * 4 * UU; // B*U
    float* h1    = h  + (size_t)BB * UU;     // B*U
    float* pre_l = h1 + (size_t)BB * UU;     // B*U
    // total: 256*6144 floats = 6.29 MB

    hipMemcpyAsync(h, h0, (size_t)BB * UU * sizeof(float),
                   hipMemcpyDeviceToDevice, stream);

    dim3 blk(256);
    dim3 grid_e(BB * UU / 256);
    for (int t = 0; t < TT; ++t) {
        // xg_t = x[:,t,:] @ kernel + bias[0]        (256x256x2560)
        gemm_bias<<<dim3(5 * UU / 64, BB / 32), blk, 0, stream>>>(
            x + (size_t)t * DD, TT * DD, kernel, bias, xg, DD, 5 * UU);
        // hg = h @ rk + bias[1][:2048]              (256x512x2048)
        gemm_bias<<<dim3(4 * UU / 64, BB / 32), blk, 0, stream>>>(
            h, UU, rk, bias + 5 * UU, hg, UU, 4 * UU);
        elem_gates<<<grid_e, blk, 0, stream>>>(xg, hg, h, h1, pre_l);
        // tg0 = h1 @ tk[0] + tb[0]                  (256x512x1536)
        gemm_bias<<<dim3(3 * UU / 64, BB / 32), blk, 0, stream>>>(
            h1, UU, tk, tb, tg, UU, 3 * UU);
        elem_t<<<grid_e, blk, 0, stream>>>(tg, h1);
        // tg1 = h1 @ tk[1] + tb[1]
        gemm_bias<<<dim3(3 * UU / 64, BB / 32), blk, 0, stream>>>(
            h1, UU, tk + (size_t)UU * 3 * UU, tb + 3 * UU, tg, UU, 3 * UU);
        elem_final<<<grid_e, blk, 0, stream>>>(tg, pre_l, xg, h1, h, out, t);
    }
}

// Round 2
// 10785.844 us; speedup vs baseline: 1.2368x; 1.2368x over previous
//
#include <hip/hip_runtime.h>
#include <math.h>

#define BB 256   // batch
#define TT 128   // time steps
#define DD 256   // input dim
#define UU 512   // units
#define G5 (5 * UU)   // 2560
#define G4 (4 * UU)   // 2048 (packed width for rk and tk)

__device__ __forceinline__ float hsig(float x) {
    return fminf(fmaxf(0.2f * x + 0.5f, 0.0f), 1.0f);
}

// ---------------------------------------------------------------------------
// Pack weights into gate-interleaved layout: col = u*4 + g
//   rkp[k][u*4+g]  = rk[k][g*U+u]              (g<4)
//   tkpX[k][u*4+g] = tk[X][k][g*U+u] (g<3), 0  (g==3 pad)
// One-time per launch (~3 MB reads). Enables per-thread gate fusion.
// ---------------------------------------------------------------------------
__global__ __launch_bounds__(256) void pack_weights(
    const float* __restrict__ rk, const float* __restrict__ tk,
    float* __restrict__ rkp, float* __restrict__ tkp0, float* __restrict__ tkp1)
{
    int idx = blockIdx.x * 256 + threadIdx.x;   // 0 .. 512*2048
    int k = idx >> 11;
    int c = idx & 2047;
    int u = c >> 2;
    int g = c & 3;
    rkp[idx] = rk[k * G4 + g * UU + u];
    float t0 = 0.f, t1 = 0.f;
    if (g < 3) {
        t0 = tk[(size_t)k * (3 * UU) + g * UU + u];
        t1 = tk[(size_t)(UU + k) * (3 * UU) + g * UU + u];
    }
    tkp0[idx] = t0;
    tkp1[idx] = t1;
}

// ---------------------------------------------------------------------------
// xg chunk GEMM: for tt in [0,tc), b in [0,B):  row r = tt*B + b
//   xg[r][0:5U] = x[b][t0+tt][:] @ kernel + bias0
// BM=64, BN=64, BK=16, 256 threads, 4x4 microtile.
// ---------------------------------------------------------------------------
__global__ __launch_bounds__(256) void gemm_xg(
    const float* __restrict__ x, const float* __restrict__ W,
    const float* __restrict__ bias0, float* __restrict__ xg, int t0)
{
    __shared__ float As[16][64];
    __shared__ float Ws[16][64];
    const int bn = blockIdx.x * 64;
    const int bm = blockIdx.y * 64;
    const int tid = threadIdx.x;
    const int tx = tid & 15;
    const int ty = tid >> 4;

    const int ar = tid >> 2;          // 0..63
    const int ac = (tid & 3) * 4;     // 0,4,8,12
    const int gr = bm + ar;
    const int ab = (gr & 255);            // b
    const int at = t0 + (gr >> 8);        // t
    const float* arow = x + ((size_t)ab * TT + at) * DD;

    const int wr = tid >> 4;          // 0..15
    const int wc = (tid & 15) * 4;

    float acc[4][4] = {};

    for (int k0 = 0; k0 < DD; k0 += 16) {
        float4 av = *(const float4*)(arow + k0 + ac);
        float4 wv = *(const float4*)(W + (size_t)(k0 + wr) * G5 + bn + wc);
        As[ac][ar] = av.x; As[ac + 1][ar] = av.y;
        As[ac + 2][ar] = av.z; As[ac + 3][ar] = av.w;
        *(float4*)&Ws[wr][wc] = wv;
        __syncthreads();
#pragma unroll
        for (int kk = 0; kk < 16; ++kk) {
            float4 a = *(const float4*)&As[kk][ty * 4];
            float4 w = *(const float4*)&Ws[kk][tx * 4];
            float av_[4] = {a.x, a.y, a.z, a.w};
            float wv_[4] = {w.x, w.y, w.z, w.w};
#pragma unroll
            for (int i = 0; i < 4; ++i)
#pragma unroll
                for (int j = 0; j < 4; ++j)
                    acc[i][j] += av_[i] * wv_[j];
        }
        __syncthreads();
    }

    float4 bv = *(const float4*)(bias0 + bn + tx * 4);
#pragma unroll
    for (int i = 0; i < 4; ++i) {
        int r = bm + ty * 4 + i;
        float4 o = {acc[i][0] + bv.x, acc[i][1] + bv.y,
                    acc[i][2] + bv.z, acc[i][3] + bv.w};
        *(float4*)(xg + (size_t)r * G5 + bn + tx * 4) = o;
    }
}

// ---------------------------------------------------------------------------
// Fused recurrent GEMM + gates.
//   hg = h @ rkp  (packed: each thread's 4 accs = 4 gates of one u)
//   z = hsig(xz+hz); r = hsig(xr+hr); hh = tanh(xh + r*hhr)
//   h1a = z*h + (1-z)*hh ; pre_l = xl + hl
// BM=32, 16 u per block (64 packed cols), BK=16, 256 threads, 2 rows/thread.
// ---------------------------------------------------------------------------
__global__ __launch_bounds__(256) void gemm_recur(
    const float* __restrict__ h, const float* __restrict__ rkp,
    const float* __restrict__ bias1, const float* __restrict__ xg_t,
    float* __restrict__ h1a, float* __restrict__ pre_l)
{
    __shared__ float As[16][32];
    __shared__ float Ws[16][64];
    const int un = blockIdx.x * 16;          // u block start
    const int bm = blockIdx.y * 32;
    const int tid = threadIdx.x;
    const int tx = tid & 15;                 // u-local
    const int ty = tid >> 4;                 // row group

    const int ar = tid >> 3;                 // 0..31
    const int ac = (tid & 7) * 2;            // 0..14
    const int wr = tid >> 4;                 // 0..15
    const int wc = (tid & 15) * 4;

    float acc[2][4] = {};

    for (int k0 = 0; k0 < UU; k0 += 16) {
        float2 av = *(const float2*)(h + (size_t)(bm + ar) * UU + k0 + ac);
        float4 wv = *(const float4*)(rkp + (size_t)(k0 + wr) * G4 + un * 4 + wc);
        As[ac][ar] = av.x; As[ac + 1][ar] = av.y;
        *(float4*)&Ws[wr][wc] = wv;
        __syncthreads();
#pragma unroll
        for (int kk = 0; kk < 16; ++kk) {
            float a0 = As[kk][ty * 2];
            float a1 = As[kk][ty * 2 + 1];
            float4 w = *(const float4*)&Ws[kk][tx * 4];
            acc[0][0] += a0 * w.x; acc[0][1] += a0 * w.y;
            acc[0][2] += a0 * w.z; acc[0][3] += a0 * w.w;
            acc[1][0] += a1 * w.x; acc[1][1] += a1 * w.y;
            acc[1][2] += a1 * w.z; acc[1][3] += a1 * w.w;
        }
        __syncthreads();
    }

    const int u = un + tx;
    const float bz = bias1[u], br = bias1[UU + u];
    const float bh = bias1[2 * UU + u], bl = bias1[3 * UU + u];
#pragma unroll
    for (int i = 0; i < 2; ++i) {
        int row = bm + ty * 2 + i;
        const float* xr_ = xg_t + (size_t)row * G5;
        float z  = hsig(xr_[u] + acc[i][0] + bz);
        float r  = hsig(xr_[UU + u] + acc[i][1] + br);
        float hh = tanhf(xr_[2 * UU + u] + r * (acc[i][2] + bh));
        float hold = h[(size_t)row * UU + u];
        h1a[(size_t)row * UU + u] = z * hold + (1.0f - z) * hh;
        pre_l[(size_t)row * UU + u] = xr_[3 * UU + u] + acc[i][3] + bl;
    }
}

// ---------------------------------------------------------------------------
// Fused transition GEMM + gates. If !is_final:
//   h1out = zt*h1in + (1-zt)*tanh(rt*th)
// If is_final, additionally apply output gate and write h + out:
//   l = hsig(pre_l); ho = l*h1'' + (1-l)*tanh(xl2)
// ---------------------------------------------------------------------------
__global__ __launch_bounds__(256) void gemm_trans(
    const float* __restrict__ h1in, const float* __restrict__ tkp,
    const float* __restrict__ tbias,
    float* __restrict__ h1out,               // used when !is_final
    const float* __restrict__ pre_l,         // final only
    const float* __restrict__ xg_t,          // final only
    float* __restrict__ hnew,                // final only
    float* __restrict__ out, int t, int is_final)
{
    __shared__ float As[16][32];
    __shared__ float Ws[16][64];
    const int un = blockIdx.x * 16;
    const int bm = blockIdx.y * 32;
    const int tid = threadIdx.x;
    const int tx = tid & 15;
    const int ty = tid >> 4;

    const int ar = tid >> 3;
    const int ac = (tid & 7) * 2;
    const int wr = tid >> 4;
    const int wc = (tid & 15) * 4;

    float acc[2][4] = {};

    for (int k0 = 0; k0 < UU; k0 += 16) {
        float2 av = *(const float2*)(h1in + (size_t)(bm + ar) * UU + k0 + ac);
        float4 wv = *(const float4*)(tkp + (size_t)(k0 + wr) * G4 + un * 4 + wc);
        As[ac][ar] = av.x; As[ac + 1][ar] = av.y;
        *(float4*)&Ws[wr][wc] = wv;
        __syncthreads();
#pragma unroll
        for (int kk = 0; kk < 16; ++kk) {
            float a0 = As[kk][ty * 2];
            float a1 = As[kk][ty * 2 + 1];
            float4 w = *(const float4*)&Ws[kk][tx * 4];
            acc[0][0] += a0 * w.x; acc[0][1] += a0 * w.y;
            acc[0][2] += a0 * w.z; acc[0][3] += a0 * w.w;
            acc[1][0] += a1 * w.x; acc[1][1] += a1 * w.y;
            acc[1][2] += a1 * w.z; acc[1][3] += a1 * w.w;
        }
        __syncthreads();
    }

    const int u = un + tx;
    const float bz = tbias[u], br = tbias[UU + u], bh = tbias[2 * UU + u];
#pragma unroll
    for (int i = 0; i < 2; ++i) {
        int row = bm + ty * 2 + i;
        float zt = hsig(acc[i][0] + bz);
        float rt = hsig(acc[i][1] + br);
        float ht = tanhf(rt * (acc[i][2] + bh));
        float h1v = zt * h1in[(size_t)row * UU + u] + (1.0f - zt) * ht;
        if (!is_final) {
            h1out[(size_t)row * UU + u] = h1v;
        } else {
            float l = hsig(pre_l[(size_t)row * UU + u]);
            float xl2 = xg_t[(size_t)row * G5 + 4 * UU + u];
            float ho = l * h1v + (1.0f - l) * tanhf(xl2);
            hnew[(size_t)row * UU + u] = ho;
            out[((size_t)row * TT + t) * UU + u] = ho;
        }
    }
}

extern "C" void kernel_launch(void* const* d_in, const int* in_sizes, int n_in,
                              void* d_out, int out_size, void* d_ws, size_t ws_size,
                              hipStream_t stream) {
    const float* x      = (const float*)d_in[0];  // (B,T,D)
    const float* h0     = (const float*)d_in[1];  // (B,U)
    const float* kernel = (const float*)d_in[2];  // (D,5U)
    const float* rk     = (const float*)d_in[3];  // (U,4U)
    const float* tk     = (const float*)d_in[4];  // (2,U,3U)
    const float* bias   = (const float*)d_in[5];  // (2,5U)
    const float* tb     = (const float*)d_in[6];  // (2,3U)
    float* out = (float*)d_out;
    float* ws  = (float*)d_ws;

    // workspace layout (floats)
    float* rkp   = ws;                               // 512*2048 = 1,048,576
    float* tkp0  = rkp  + (size_t)UU * G4;           // 1,048,576
    float* tkp1  = tkp0 + (size_t)UU * G4;           // 1,048,576
    float* h     = tkp1 + (size_t)UU * G4;           // B*U = 131,072
    float* h1a   = h    + (size_t)BB * UU;
    float* h1b   = h1a  + (size_t)BB * UU;
    float* pre_l = h1b  + (size_t)BB * UU;
    float* xgbuf = pre_l + (size_t)BB * UU;          // TC * B * 5U
    size_t fixed_floats = (size_t)(xgbuf - ws);
    size_t ws_floats = ws_size / sizeof(float);
    size_t per_step = (size_t)BB * G5;               // 655,360 floats (2.62 MB)
    int TC = 1;
    if (ws_floats > fixed_floats + per_step) {
        size_t tc = (ws_floats - fixed_floats) / per_step;
        TC = (int)(tc > 128 ? 128 : tc);
    }

    const float* bias0 = bias;
    const float* bias1 = bias + G5;
    const float* tb0 = tb;
    const float* tb1 = tb + 3 * UU;

    pack_weights<<<dim3((UU * G4) / 256), dim3(256), 0, stream>>>(rk, tk, rkp, tkp0, tkp1);
    hipMemcpyAsync(h, h0, (size_t)BB * UU * sizeof(float),
                   hipMemcpyDeviceToDevice, stream);

    dim3 blk(256);
    dim3 grid_s(UU / 16, BB / 32);   // 32 x 8 = 256 blocks for scan GEMMs
    for (int t0 = 0; t0 < TT; t0 += TC) {
        int tc = (t0 + TC <= TT) ? TC : (TT - t0);
        gemm_xg<<<dim3(G5 / 64, tc * (BB / 64)), blk, 0, stream>>>(
            x, kernel, bias0, xgbuf, t0);
        for (int tt = 0; tt < tc; ++tt) {
            int t = t0 + tt;
            const float* xg_t = xgbuf + (size_t)tt * BB * G5;
            gemm_recur<<<grid_s, blk, 0, stream>>>(
                h, rkp, bias1, xg_t, h1a, pre_l);
            gemm_trans<<<grid_s, blk, 0, stream>>>(
                h1a, tkp0, tb0, h1b, nullptr, nullptr, nullptr, nullptr, 0, 0);
            gemm_trans<<<grid_s, blk, 0, stream>>>(
                h1b, tkp1, tb1, nullptr, pre_l, xg_t, h, out, t, 1);
        }
    }
}